// Round 5
// baseline (262.009 us; speedup 1.0000x reference)
//
#include <hip/hip_runtime.h>
#include <hip/hip_bf16.h>

// Problem constants
#define Bsz 4
#define Tseq 2048
#define Cdim 1024
#define NH 16
#define HD 64
#define Mrows (Bsz*Tseq)      // 8192
#define N3C (3*Cdim)          // 3072

typedef __attribute__((ext_vector_type(8))) short short8;
typedef __attribute__((ext_vector_type(4))) short short4v;
typedef __attribute__((ext_vector_type(4))) float float4v;

__device__ __forceinline__ unsigned short f2b(float f) {
    union { float f; unsigned u; } x; x.f = f;
    unsigned u = x.u;
    u += 0x7fff + ((u >> 16) & 1);   // true RNE to bf16
    return (unsigned short)(u >> 16);
}

// pack 2 floats -> bf16x2 dword (RNE)
__device__ __forceinline__ unsigned pk2bf(float a, float b) {
#if __has_builtin(__builtin_amdgcn_cvt_pk_bf16_f32)
    auto w = __builtin_amdgcn_cvt_pk_bf16_f32(a, b);
    unsigned u; __builtin_memcpy(&u, &w, 4);
    return u;
#else
    return (unsigned)f2b(a) | ((unsigned)f2b(b) << 16);
#endif
}

// async global->LDS, 16B per lane; lds dst must be wave-uniform (HW adds lane*16)
#define GLDS(gp, lp) __builtin_amdgcn_global_load_lds(                         \
    (const __attribute__((address_space(1))) unsigned*)(gp),                   \
    (__attribute__((address_space(3))) unsigned*)(lp), 16, 0, 0)

// ---------------- cast x: f32 -> bf16 ----------------
__global__ __launch_bounds__(256) void cast_kernel(const float* __restrict__ in,
                                                   unsigned short* __restrict__ out, int n) {
    int i = (blockIdx.x * 256 + threadIdx.x) * 4;
    if (i < n) {
        float4 v = *reinterpret_cast<const float4*>(in + i);
        ushort4 o;
        o.x = f2b(v.x); o.y = f2b(v.y); o.z = f2b(v.z); o.w = f2b(v.w);
        *reinterpret_cast<ushort4*>(out + i) = o;
    }
}

// ---------------- transpose + cast: W[K][N] f32 -> Wt[N][K] bf16 ----------------
__global__ __launch_bounds__(256) void transpose_cast(const float* __restrict__ in,
                                                      unsigned short* __restrict__ out,
                                                      int K, int N) {
    __shared__ float tile[32][33];
    int n0 = blockIdx.x * 32, k0 = blockIdx.y * 32;
    int tx = threadIdx.x & 31, ty = threadIdx.x >> 5;   // 8 rows per pass
    #pragma unroll
    for (int i = 0; i < 32; i += 8)
        tile[ty + i][tx] = in[(k0 + ty + i) * N + n0 + tx];
    __syncthreads();
    #pragma unroll
    for (int i = 0; i < 32; i += 8)
        out[(size_t)(n0 + ty + i) * K + k0 + tx] = f2b(tile[tx][ty + i]);
}

// ======== bf16 MFMA GEMM, 4-phase 256x128, triple-buffered (QKV + proj) ========
// BM=256, BN=128, BK=64, 512 thr (8 waves, 4M x 2N -> wave tile 64x64).
// Triple-buffered LDS (144 KiB): during tile t, stage tile t+2 (6 GLDS/thread,
// spread over the 4 phases); boundary wait vmcnt(6) drains tile t+1 COMPLETELY
// (all halves resident before any t+1 read -- race-free by construction) while
// tile t+2's 6 loads stay in flight across the barrier.  Never 0 in the loop.
// Each phase: {ds_read frags || stage} -> s_barrier -> lgkmcnt(0)+sched_barrier
// -> setprio(1) 8xMFMA setprio(0) -> s_barrier.
// Both-sides 16B-granule XOR swizzle (g ^ (row&7)): linear DMA dst with
// pre-swizzled global source; swizzled frag reads -> conflict-free b128.
// Grid: QKV 32x24=768 (3 exact rounds of 256 CUs), proj 32x8=256 (1 round).

template<bool QKV>
__global__ __launch_bounds__(512, 2) void gemm4p(const unsigned short* __restrict__ A,
                                                 const unsigned short* __restrict__ Bt,
                                                 const float* __restrict__ bias,
                                                 unsigned short* __restrict__ qb,
                                                 unsigned short* __restrict__ kb,
                                                 unsigned short* __restrict__ vb,
                                                 float* __restrict__ out) {
    __shared__ unsigned short As[3][256 * 64];   // 96 KiB
    __shared__ unsigned short Bs[3][128 * 64];   // 48 KiB

    int tid = threadIdx.x;
    int lane = tid & 63, wave = tid >> 6;        // 8 waves
    int wm = wave >> 1, wn = wave & 1;           // 4M x 2N
    int l15 = lane & 15, quad = lane >> 4;
    int sx = l15 & 7;

    // XCD-panel swizzle: rowblk groups of 4 per XCD
    int f = blockIdx.x;
    int xcd = f & 7, slot = f >> 3;
    int rowblk = xcd * 4 + (slot & 3);           // 0..31
    int colblk = slot >> 2;
    int row0 = rowblk * 256;
    int col0 = colblk * 128;

    // staging: lane -> row +(lane>>3), swizzled source granule ((lane&7)^srow)*8
    int srow = lane >> 3;
    int gsw = ((lane & 7) ^ srow) * 8;
    const unsigned short* Ag = A + (size_t)(row0 + srow) * Cdim + gsw;
    const unsigned short* Bg = Bt + (size_t)(col0 + srow) * Cdim + gsw;

    // stage chunk c (64 rows) of k-offset kk into buffer sb; 1 GLDS/thread,
    // each wave covers rows c*64 + wave*8 .. +8
    #define STG_A(c, kk, sb)                                                    \
        GLDS(Ag + (size_t)((c) * 64 + wave * 8) * Cdim + (kk),                  \
             &As[sb][((c) * 64 + wave * 8) * 64])
    #define STG_B(c, kk, sb)                                                    \
        GLDS(Bg + (size_t)((c) * 64 + wave * 8) * Cdim + (kk),                  \
             &Bs[sb][((c) * 64 + wave * 8) * 64])
    #define STG_ALL(kk, sb) do {                                                \
        STG_A(0, kk, sb); STG_A(1, kk, sb); STG_A(2, kk, sb); STG_A(3, kk, sb); \
        STG_B(0, kk, sb); STG_B(1, kk, sb);                                     \
    } while (0)

    float4v acc[4][4] = {};
    short8 af0[4], af1[4];                       // A-frags kg=0 / kg=1, both live

    // prologue: tiles 0 and 1; drain tile 0 (tile 1's 6 stay in flight)
    STG_ALL(0, 0);
    STG_ALL(64, 1);
    asm volatile("s_waitcnt vmcnt(6)" ::: "memory");
    __builtin_amdgcn_s_barrier();

    int gc0 = (quad ^ sx) * 8;                   // frag col granule, kg=0
    int gc1 = ((4 + quad) ^ sx) * 8;             // frag col granule, kg=1
    int arow = (wm * 64 + l15) * 64;             // A frag base (row stride 16 -> +1024)
    int brow = (wn * 64 + l15) * 64;             // B frag base

    int bc = 0, bp = 2;                          // compute buf, prefetch buf
    #pragma unroll 1
    for (int t = 0; t < 16; ++t) {
        int kn = ((t + 2) & 15) * 64;            // wrap prefetch at tail (benign)
        const unsigned short* Asb = &As[bc][0];
        const unsigned short* Bsb = &Bs[bc][0];

        // ---- P0: kg=0, nj=0..1 : read af0[4] + bf ; stage A chunks 0,1 (t+2) ----
        {
            short8 bf[2];
            #pragma unroll
            for (int mi = 0; mi < 4; mi++)
                af0[mi] = *(const short8*)&Asb[arow + mi * 1024 + gc0];
            #pragma unroll
            for (int nj = 0; nj < 2; nj++)
                bf[nj] = *(const short8*)&Bsb[brow + nj * 1024 + gc0];
            STG_A(0, kn, bp); STG_A(1, kn, bp);
            __builtin_amdgcn_s_barrier();
            asm volatile("s_waitcnt lgkmcnt(0)" ::: "memory");
            __builtin_amdgcn_sched_barrier(0);
            __builtin_amdgcn_s_setprio(1);
            #pragma unroll
            for (int mi = 0; mi < 4; mi++)
                #pragma unroll
                for (int nj = 0; nj < 2; nj++)
                    acc[mi][nj] = __builtin_amdgcn_mfma_f32_16x16x32_bf16(af0[mi], bf[nj], acc[mi][nj], 0, 0, 0);
            __builtin_amdgcn_s_setprio(0);
            __builtin_amdgcn_s_barrier();
        }
        // ---- P1: kg=1, nj=0..1 : read af1[4] + bf ; stage A chunks 2,3 ----
        {
            short8 bf[2];
            #pragma unroll
            for (int mi = 0; mi < 4; mi++)
                af1[mi] = *(const short8*)&Asb[arow + mi * 1024 + gc1];
            #pragma unroll
            for (int nj = 0; nj < 2; nj++)
                bf[nj] = *(const short8*)&Bsb[brow + nj * 1024 + gc1];
            STG_A(2, kn, bp); STG_A(3, kn, bp);
            __builtin_amdgcn_s_barrier();
            asm volatile("s_waitcnt lgkmcnt(0)" ::: "memory");
            __builtin_amdgcn_sched_barrier(0);
            __builtin_amdgcn_s_setprio(1);
            #pragma unroll
            for (int mi = 0; mi < 4; mi++)
                #pragma unroll
                for (int nj = 0; nj < 2; nj++)
                    acc[mi][nj] = __builtin_amdgcn_mfma_f32_16x16x32_bf16(af1[mi], bf[nj], acc[mi][nj], 0, 0, 0);
            __builtin_amdgcn_s_setprio(0);
            __builtin_amdgcn_s_barrier();
        }
        // ---- P2: kg=1, nj=2..3 : read bf only ; stage B chunk 0 ----
        {
            short8 bf[2];
            #pragma unroll
            for (int nj = 0; nj < 2; nj++)
                bf[nj] = *(const short8*)&Bsb[brow + (2 + nj) * 1024 + gc1];
            STG_B(0, kn, bp);
            __builtin_amdgcn_s_barrier();
            asm volatile("s_waitcnt lgkmcnt(0)" ::: "memory");
            __builtin_amdgcn_sched_barrier(0);
            __builtin_amdgcn_s_setprio(1);
            #pragma unroll
            for (int mi = 0; mi < 4; mi++)
                #pragma unroll
                for (int nj = 0; nj < 2; nj++)
                    acc[mi][2 + nj] = __builtin_amdgcn_mfma_f32_16x16x32_bf16(af1[mi], bf[nj], acc[mi][2 + nj], 0, 0, 0);
            __builtin_amdgcn_s_setprio(0);
            __builtin_amdgcn_s_barrier();
        }
        // ---- P3: kg=0, nj=2..3 : read bf only ; stage B chunk 1 ; boundary vmcnt(6) ----
        {
            short8 bf[2];
            #pragma unroll
            for (int nj = 0; nj < 2; nj++)
                bf[nj] = *(const short8*)&Bsb[brow + (2 + nj) * 1024 + gc0];
            STG_B(1, kn, bp);
            __builtin_amdgcn_s_barrier();
            asm volatile("s_waitcnt lgkmcnt(0)" ::: "memory");
            __builtin_amdgcn_sched_barrier(0);
            __builtin_amdgcn_s_setprio(1);
            #pragma unroll
            for (int mi = 0; mi < 4; mi++)
                #pragma unroll
                for (int nj = 0; nj < 2; nj++)
                    acc[mi][2 + nj] = __builtin_amdgcn_mfma_f32_16x16x32_bf16(af0[mi], bf[nj], acc[mi][2 + nj], 0, 0, 0);
            __builtin_amdgcn_s_setprio(0);
            // boundary: drain tile t+1's 6 loads; keep tile t+2's 6 in flight
            asm volatile("s_waitcnt vmcnt(6)" ::: "memory");
            __builtin_amdgcn_s_barrier();
        }

        bc = (bc == 2) ? 0 : bc + 1;
        bp = (bp == 2) ? 0 : bp + 1;
    }
    // retire dangling wrap-prefetch DMAs before block exit
    asm volatile("s_waitcnt vmcnt(0)" ::: "memory");
    #undef STG_A
    #undef STG_B
    #undef STG_ALL

    // epilogue: wave tile 64x64 at (wm*64, wn*64)
    #pragma unroll
    for (int mi = 0; mi < 4; mi++) {
        #pragma unroll
        for (int nj = 0; nj < 4; nj++) {
            int colb = col0 + wn * 64 + nj * 16 + l15;
            int rowb = row0 + wm * 64 + mi * 16 + quad * 4;
            if (QKV) {
                int p = colb >> 10;          // 0=q 1=k 2=v
                int h = (colb & 1023) >> 6;
                int d = colb & 63;
                int b = rowb >> 11;
                int t = rowb & 2047;
                if (p == 2) {
                    // V transposed [bh][d][T]: r-values are t-consecutive -> ushort4
                    ushort4 pk;
                    pk.x = f2b(acc[mi][nj][0] + bias[colb]);
                    pk.y = f2b(acc[mi][nj][1] + bias[colb]);
                    pk.z = f2b(acc[mi][nj][2] + bias[colb]);
                    pk.w = f2b(acc[mi][nj][3] + bias[colb]);
                    *(ushort4*)&vb[((size_t)(b * NH + h) * HD + d) * Tseq + t] = pk;
                } else {
                    unsigned short* dst = (p == 0) ? qb : kb;
                    #pragma unroll
                    for (int r = 0; r < 4; r++)
                        dst[((size_t)(b * NH + h) * Tseq + (t + r)) * HD + d] =
                            f2b(acc[mi][nj][r] + bias[colb]);
                }
            } else {
                #pragma unroll
                for (int r = 0; r < 4; r++)
                    out[(size_t)(rowb + r) * Cdim + colb] = acc[mi][nj][r] + bias[colb];
            }
        }
    }
}

// ---------------- flash attention (causal), bf16 MFMA ----------------
// 4-wave blocks (256 thr), q-tile = 128 rows (32/wave), 64-key windows,
// double-buffered K/V LDS with 2-phase pipeline; XOR-swizzled staging;
// S^T register trick; defer-rescale.

__global__ __launch_bounds__(256, 4) void attn_kernel(const unsigned short* __restrict__ qb,
                                                      const unsigned short* __restrict__ kb,
                                                      const unsigned short* __restrict__ vt,
                                                      unsigned short* __restrict__ yb) {
    __shared__ unsigned short Ks[2][64 * 64];   // [buf][key][64d], swizzled
    __shared__ unsigned short Vs[2][64 * 64];   // [buf][d][64key], swizzled

    int tid = threadIdx.x;
    int lane = tid & 63, wave = tid >> 6;      // 4 waves
    int l15 = lane & 15, quad = lane >> 4;
    int bh = blockIdx.x;
    int qt = 15 - blockIdx.y;

    const unsigned short* Qh = qb + (size_t)bh * Tseq * HD;
    const unsigned short* Kh = kb + (size_t)bh * Tseq * HD;
    const unsigned short* Vh = vt + (size_t)bh * HD * Tseq;
    int b = bh >> 4, h = bh & 15;
    const float cexp = 0.18033688011112042f;   // 0.125 * log2(e)

    int q0 = qt * 128;
    int rb0 = q0 + wave * 32;

    short8 qf[2][2];
    #pragma unroll
    for (int mi = 0; mi < 2; mi++)
        #pragma unroll
        for (int g = 0; g < 2; g++)
            qf[mi][g] = *(const short8*)(Qh + (size_t)(rb0 + mi * 16 + l15) * HD + g * 32 + quad * 8);

    int srow = lane >> 3;
    int scol = ((lane & 7) ^ srow) * 8;
    const unsigned short* Kg0 = Kh + (size_t)(wave * 16 + srow) * HD + scol;
    const unsigned short* Vg0 = Vh + (size_t)(wave * 16 + srow) * Tseq + scol;
    unsigned short* Kl0 = &Ks[0][wave * 1024];
    unsigned short* Vl0 = &Vs[0][wave * 1024];
    unsigned short* Kl1 = &Ks[1][wave * 1024];
    unsigned short* Vl1 = &Vs[1][wave * 1024];

    int sx = l15 & 7;
    int kx0 = (quad ^ sx) * 8;
    int kx1 = ((4 + quad) ^ sx) * 8;
    int qh_ = quad >> 1, ql_ = quad & 1;

    float4v ov[2][4] = {};
    float m[2]  = {-1e30f, -1e30f};
    float lp[2] = {0.f, 0.f};

    int nw = (q0 >> 6) + 2;

    GLDS(Kg0, Kl0);                GLDS(Kg0 + 8 * HD, Kl0 + 512);
    GLDS(Vg0, Vl0);                GLDS(Vg0 + 8 * Tseq, Vl0 + 512);
    __syncthreads();

    #pragma unroll 1
    for (int it = 0; it < nw; ++it) {
        int j0 = it << 6;

        if (it + 1 < nw) {
            int jn = j0 + 64;
            unsigned short* Kl = (it & 1) ? Kl0 : Kl1;
            unsigned short* Vl = (it & 1) ? Vl0 : Vl1;
            GLDS(Kg0 + (size_t)jn * HD, Kl);
            GLDS(Kg0 + (size_t)(jn + 8) * HD, Kl + 512);
            GLDS(Vg0 + jn, Vl);
            GLDS(Vg0 + 8 * Tseq + jn, Vl + 512);
        }

        if (j0 <= rb0 + 31) {
            const unsigned short* Kl = &Ks[it & 1][0];
            const unsigned short* Vl = &Vs[it & 1][0];

            float4v st[2][4];
            #pragma unroll
            for (int mi = 0; mi < 2; mi++)
                #pragma unroll
                for (int kg = 0; kg < 4; kg++)
                    st[mi][kg] = (float4v){0.f, 0.f, 0.f, 0.f};
            #pragma unroll
            for (int kg = 0; kg < 4; kg++) {
                int krow = kg * 1024 + l15 * 64;
                short8 kf0 = *(const short8*)&Kl[krow + kx0];
                short8 kf1 = *(const short8*)&Kl[krow + kx1];
                st[0][kg] = __builtin_amdgcn_mfma_f32_16x16x32_bf16(kf0, qf[0][0], st[0][kg], 0, 0, 0);
                st[0][kg] = __builtin_amdgcn_mfma_f32_16x16x32_bf16(kf1, qf[0][1], st[0][kg], 0, 0, 0);
                st[1][kg] = __builtin_amdgcn_mfma_f32_16x16x32_bf16(kf0, qf[1][0], st[1][kg], 0, 0, 0);
                st[1][kg] = __builtin_amdgcn_mfma_f32_16x16x32_bf16(kf1, qf[1][1], st[1][kg], 0, 0, 0);
            }

            if (j0 + 63 > rb0) {
                #pragma unroll
                for (int mi = 0; mi < 2; mi++) {
                    int qrow = rb0 + mi * 16 + l15;
                    #pragma unroll
                    for (int kg = 0; kg < 4; kg++) {
                        int keyb = j0 + kg * 16 + quad * 4;
                        #pragma unroll
                        for (int r = 0; r < 4; r++)
                            if (keyb + r > qrow) st[mi][kg][r] = -1e30f;
                    }
                }
            }

            short4v pf[2][4];
            #pragma unroll
            for (int mi = 0; mi < 2; mi++) {
                float mx = st[mi][0][0];
                #pragma unroll
                for (int kg = 0; kg < 4; kg++)
                    #pragma unroll
                    for (int r = 0; r < 4; r++)
                        mx = fmaxf(mx, st[mi][kg][r]);
                mx = fmaxf(mx, __shfl_xor(mx, 16));
                mx = fmaxf(mx, __shfl_xor(mx, 32));
                if (__any(mx > m[mi] + 16.0f)) {
                    float mn = fmaxf(m[mi], mx);
                    float alv = __builtin_amdgcn_exp2f((m[mi] - mn) * cexp);
                    m[mi] = mn;
                    lp[mi] *= alv;
                    float ar_[4];
                    #pragma unroll
                    for (int r = 0; r < 4; r++)
                        ar_[r] = __shfl(alv, quad * 4 + r);
                    #pragma unroll
                    for (int dg = 0; dg < 4; dg++)
                        #pragma unroll
                        for (int r = 0; r < 4; r++)
                            ov[mi][dg][r] *= ar_[r];
                }
                float mc = -m[mi] * cexp;
                float sum = 0.f;
                #pragma unroll
                for (int kg = 0; kg < 4; kg++) {
                    float p0 = __builtin_amdgcn_exp2f(__builtin_fmaf(st[mi][kg][0], cexp, mc));
                    float p1 = __builtin_amdgcn_exp2f(__builtin_fmaf(st[mi][kg][1], cexp, mc));
                    float p2 = __builtin_amdgcn_exp2f(__builtin_fmaf(st[mi][kg][2], cexp, mc));
                    float p3 = __builtin_amdgcn_exp2f(__builtin_fmaf(st[mi][kg][3], cexp, mc));
                    sum += (p0 + p1) + (p2 + p3);
                    union { unsigned u[2]; short4v s; } pk_;
                    pk_.u[0] = pk2bf(p0, p1);
                    pk_.u[1] = pk2bf(p2, p3);
                    pf[mi][kg] = pk_.s;
                }
                lp[mi] += sum;
            }

            #pragma unroll
            for (int kg = 0; kg < 4; kg++) {
                int vx = (((kg * 2 + qh_) ^ sx) << 3) + ql_ * 4;
                #pragma unroll
                for (int dg = 0; dg < 4; dg++) {
                    short4v vf = *(const short4v*)&Vl[dg * 1024 + l15 * 64 + vx];
                    ov[0][dg] = __builtin_amdgcn_mfma_f32_16x16x16bf16_1k(pf[0][kg], vf, ov[0][dg], 0, 0, 0);
                    ov[1][dg] = __builtin_amdgcn_mfma_f32_16x16x16bf16_1k(pf[1][kg], vf, ov[1][dg], 0, 0, 0);
                }
            }
        }

        __syncthreads();
    }

    #pragma unroll
    for (int mi = 0; mi < 2; mi++) {
        float lf = lp[mi];
        lf += __shfl_xor(lf, 16);
        lf += __shfl_xor(lf, 32);
        float rinv[4];
        #pragma unroll
        for (int r = 0; r < 4; r++)
            rinv[r] = 1.0f / __shfl(lf, quad * 4 + r);
        #pragma unroll
        for (int dg = 0; dg < 4; dg++)
            #pragma unroll
            for (int r = 0; r < 4; r++) {
                int t = rb0 + mi * 16 + quad * 4 + r;
                yb[((size_t)b * Tseq + t) * Cdim + h * HD + dg * 16 + l15] =
                    f2b(ov[mi][dg][r] * rinv[r]);
            }
    }
}

extern "C" void kernel_launch(void* const* d_in, const int* in_sizes, int n_in,
                              void* d_out, int out_size, void* d_ws, size_t ws_size,
                              hipStream_t stream) {
    const float* x  = (const float*)d_in[0];
    const float* Wa = (const float*)d_in[1];
    const float* ba = (const float*)d_in[2];
    const float* Wp = (const float*)d_in[3];
    const float* bp = (const float*)d_in[4];
    float* out = (float*)d_out;

    unsigned short* ws = (unsigned short*)d_ws;
    unsigned short* xb  = ws;                          // 8192*1024
    unsigned short* Wat = xb  + (size_t)Mrows * Cdim;  // 3072*1024
    unsigned short* Wpt = Wat + (size_t)N3C * Cdim;    // 1024*1024
    unsigned short* qb  = Wpt + (size_t)Cdim * Cdim;   // [bh][T][HD]
    unsigned short* kb  = qb  + (size_t)Bsz * NH * Tseq * HD;   // [bh][T][HD]
    unsigned short* vb  = kb  + (size_t)Bsz * NH * Tseq * HD;   // [bh][HD][T]  (transposed)
    unsigned short* yb  = vb  + (size_t)Bsz * NH * Tseq * HD;

    int nx = Mrows * Cdim;
    cast_kernel<<<nx / 4 / 256, 256, 0, stream>>>(x, xb, nx);
    transpose_cast<<<dim3(N3C / 32, Cdim / 32), 256, 0, stream>>>(Wa, Wat, Cdim, N3C);
    transpose_cast<<<dim3(Cdim / 32, Cdim / 32), 256, 0, stream>>>(Wp, Wpt, Cdim, Cdim);

    // QKV: 32 rowblks x 24 colblks (256x128 tiles) = 768 blocks = 3 exact rounds
    gemm4p<true><<<768, 512, 0, stream>>>(xb, Wat, ba, qb, kb, vb, nullptr);

    attn_kernel<<<dim3(Bsz * NH, 16), 256, 0, stream>>>(qb, kb, vb, yb);

    // proj: 32 rowblks x 8 colblks = 256 blocks = 1 exact round
    gemm4p<false><<<256, 512, 0, stream>>>(yb, Wpt, bp, nullptr, nullptr, nullptr, out);
}

// Round 7
// 253.915 us; speedup vs baseline: 1.0319x; 1.0319x over previous
//
#include <hip/hip_runtime.h>
#include <hip/hip_bf16.h>

// Problem constants
#define Bsz 4
#define Tseq 2048
#define Cdim 1024
#define NH 16
#define HD 64
#define Mrows (Bsz*Tseq)      // 8192
#define N3C (3*Cdim)          // 3072

typedef __attribute__((ext_vector_type(8))) short short8;
typedef __attribute__((ext_vector_type(4))) short short4v;
typedef __attribute__((ext_vector_type(4))) float float4v;

__device__ __forceinline__ unsigned short f2b(float f) {
    union { float f; unsigned u; } x; x.f = f;
    unsigned u = x.u;
    u += 0x7fff + ((u >> 16) & 1);   // true RNE to bf16
    return (unsigned short)(u >> 16);
}

// pack 2 floats -> bf16x2 dword (RNE)
__device__ __forceinline__ unsigned pk2bf(float a, float b) {
#if __has_builtin(__builtin_amdgcn_cvt_pk_bf16_f32)
    auto w = __builtin_amdgcn_cvt_pk_bf16_f32(a, b);
    unsigned u; __builtin_memcpy(&u, &w, 4);
    return u;
#else
    return (unsigned)f2b(a) | ((unsigned)f2b(b) << 16);
#endif
}

// async global->LDS, 16B per lane; lds dst must be wave-uniform (HW adds lane*16)
#define GLDS(gp, lp) __builtin_amdgcn_global_load_lds(                         \
    (const __attribute__((address_space(1))) unsigned*)(gp),                   \
    (__attribute__((address_space(3))) unsigned*)(lp), 16, 0, 0)

// ---------------- cast x: f32 -> bf16 ----------------
__global__ __launch_bounds__(256) void cast_kernel(const float* __restrict__ in,
                                                   unsigned short* __restrict__ out, int n) {
    int i = (blockIdx.x * 256 + threadIdx.x) * 4;
    if (i < n) {
        float4 v = *reinterpret_cast<const float4*>(in + i);
        ushort4 o;
        o.x = f2b(v.x); o.y = f2b(v.y); o.z = f2b(v.z); o.w = f2b(v.w);
        *reinterpret_cast<ushort4*>(out + i) = o;
    }
}

// ---------------- transpose + cast: W[K][N] f32 -> Wt[N][K] bf16 ----------------
__global__ __launch_bounds__(256) void transpose_cast(const float* __restrict__ in,
                                                      unsigned short* __restrict__ out,
                                                      int K, int N) {
    __shared__ float tile[32][33];
    int n0 = blockIdx.x * 32, k0 = blockIdx.y * 32;
    int tx = threadIdx.x & 31, ty = threadIdx.x >> 5;   // 8 rows per pass
    #pragma unroll
    for (int i = 0; i < 32; i += 8)
        tile[ty + i][tx] = in[(k0 + ty + i) * N + n0 + tx];
    __syncthreads();
    #pragma unroll
    for (int i = 0; i < 32; i += 8)
        out[(size_t)(n0 + ty + i) * K + k0 + tx] = f2b(tile[tx][ty + i]);
}

// ========== bf16 MFMA GEMM, K-sliced 2-phase, 256-row tiles ==========
// BM=256, BN=256 (QKV, MI=8, 2M x 4N waves) or BN=128 (proj, MI=4, 4M x 2N).
// BK=64 split into two 32-wide K-SLICES; each phase consumes exactly one
// slice, so a phase's read set is one contiguous LDS region that can be
// staged + drained as a unit -> race-free COUNTED vmcnt on a double buffer
// (impossible with row-half phases: every phase reads all row-halves).
// LDS [buf][kslice][rows][32] (QKV 128 KiB, proj 96 KiB).
// Per phase (global phase index p = 2t+ph):
//   {12(8) ds_read_b128 frags || stage slice p+3 (4(3) GLDS)}
//   -> vmcnt(8|6): drains slice p+1 (next phase's data); slices p+2, p+3
//      stay in flight across TWO barriers (~2 phases of latency cover)
//   -> s_barrier -> lgkmcnt(0)+sched_barrier -> setprio(1) 32(16) MFMA
//   setprio(0) -> s_barrier.  Never drains to 0 in the loop.
// Swizzle (64B rows, 4 granules): granule ^ ((row>>1)&3); lane-constant
// forms: (l15>>1)&3 for frag reads, (lane>>3)&3 for staging source.
// 2-way bank aliasing max (free).  Both-sides consistent.

template<int MI, int BN, bool QKV>
__global__ __launch_bounds__(512, 2) void gemm2p(const unsigned short* __restrict__ A,
                                                 const unsigned short* __restrict__ Bt,
                                                 const float* __restrict__ bias,
                                                 unsigned short* __restrict__ qb,
                                                 unsigned short* __restrict__ kb,
                                                 unsigned short* __restrict__ vb,
                                                 float* __restrict__ out) {
    __shared__ unsigned short As[2][2][256 * 32];   // [buf][kslice][row][32]
    __shared__ unsigned short Bs[2][2][BN * 32];

    constexpr int WN = (MI == 8) ? 4 : 2;           // waves in N
    constexpr int SPP = 2 + BN / 128;               // GLDS per phase per thread
    constexpr int NCOLB = (QKV ? N3C : Cdim) / BN;

    int tid = threadIdx.x;
    int lane = tid & 63, wave = tid >> 6;           // 8 waves
    int wm = wave / WN, wn = wave % WN;
    int l15 = lane & 15, quad = lane >> 4;
    int wmBase = wm * (MI * 16);

    // XCD-panel swizzle: 32 row-blocks, 4 per XCD
    int f = blockIdx.x;
    int xcd = f & 7, slot = f >> 3;
    int rowblk = xcd * 4 + (slot & 3);              // 0..31
    int colblk = slot >> 2;                         // 0..NCOLB-1
    int row0 = rowblk * 256;
    int col0 = colblk * BN;
    (void)NCOLB;

    // staging: lane -> row +(lane>>2) within 16-row group, granule lane&3;
    // source granule pre-swizzled: (lane&3) ^ ((lane>>3)&3)
    int srow4 = lane >> 2;
    int gsrc = ((lane & 3) ^ ((lane >> 3) & 3)) * 8;
    const unsigned short* Ag = A + (size_t)(row0 + srow4) * Cdim + gsrc;
    const unsigned short* Bg = Bt + (size_t)(col0 + srow4) * Cdim + gsrc;

    // stage one K-slice (k-offset kk in shorts) into As/Bs[sb][sph]
    #define STG_AB(sph_, kk_, sb_) do {                                         \
        GLDS(Ag + (size_t)(wave * 16) * Cdim + (kk_),                           \
             &As[sb_][sph_][(wave * 16) * 32]);                                 \
        GLDS(Ag + (size_t)(128 + wave * 16) * Cdim + (kk_),                     \
             &As[sb_][sph_][(128 + wave * 16) * 32]);                           \
        GLDS(Bg + (size_t)(wave * 16) * Cdim + (kk_),                           \
             &Bs[sb_][sph_][(wave * 16) * 32]);                                 \
        if constexpr (BN == 256)                                                \
            GLDS(Bg + (size_t)(128 + wave * 16) * Cdim + (kk_),                 \
                 &Bs[sb_][sph_][(128 + wave * 16) * 32]);                       \
    } while (0)

    float4v acc[MI][4] = {};

    // prologue: slices 0 (t0.k0), 1 (t0.k1), 2 (t1.k0)
    STG_AB(0, 0, 0);
    STG_AB(1, 32, 0);
    STG_AB(0, 64, 1);
    if constexpr (SPP == 4) asm volatile("s_waitcnt vmcnt(8)" ::: "memory");
    else                    asm volatile("s_waitcnt vmcnt(6)" ::: "memory");
    __builtin_amdgcn_s_barrier();

    // frag-read swizzle: granule = quad ^ ((row>>1)&3) = quad ^ ((l15>>1)&3)
    int gq0 = (quad ^ ((l15 >> 1) & 3)) * 8;
    int afb = (wmBase + l15) * 32 + gq0;            // + mi*512
    int bfb = (wn * 64 + l15) * 32 + gq0;           // + nj*512

    #pragma unroll 1
    for (int t = 0; t < 16; ++t) {
        #pragma unroll
        for (int ph = 0; ph < 2; ++ph) {
            int bc = t & 1;
            const unsigned short* Asl = &As[bc][ph][0];
            const unsigned short* Bsl = &Bs[bc][ph][0];

            short8 af[MI], bf[4];
            #pragma unroll
            for (int mi = 0; mi < MI; mi++)
                af[mi] = *(const short8*)&Asl[afb + mi * 512];
            #pragma unroll
            for (int nj = 0; nj < 4; nj++)
                bf[nj] = *(const short8*)&Bsl[bfb + nj * 512];

            // stage slice p+3 (wrap at tail re-stages early slices; WAR-safe)
            int s = (2 * t + ph + 3) & 31;
            int st_ = s >> 1, sph = s & 1, sb = st_ & 1;
            STG_AB(sph, st_ * 64 + sph * 32, sb);

            // counted drain: slice p+1 resident; p+2, p+3 stay in flight
            if constexpr (SPP == 4) asm volatile("s_waitcnt vmcnt(8)" ::: "memory");
            else                    asm volatile("s_waitcnt vmcnt(6)" ::: "memory");
            __builtin_amdgcn_s_barrier();
            asm volatile("s_waitcnt lgkmcnt(0)" ::: "memory");
            __builtin_amdgcn_sched_barrier(0);
            __builtin_amdgcn_s_setprio(1);
            #pragma unroll
            for (int mi = 0; mi < MI; mi++)
                #pragma unroll
                for (int nj = 0; nj < 4; nj++)
                    acc[mi][nj] = __builtin_amdgcn_mfma_f32_16x16x32_bf16(af[mi], bf[nj], acc[mi][nj], 0, 0, 0);
            __builtin_amdgcn_s_setprio(0);
            __builtin_amdgcn_s_barrier();
        }
    }
    // retire dangling wrap-prefetch DMAs before block exit
    asm volatile("s_waitcnt vmcnt(0)" ::: "memory");
    #undef STG_AB

    // epilogue: wave tile (MI*16) x 64 at (wmBase, wn*64)
    #pragma unroll
    for (int mi = 0; mi < MI; mi++) {
        #pragma unroll
        for (int nj = 0; nj < 4; nj++) {
            int colb = col0 + wn * 64 + nj * 16 + l15;
            int rowb = row0 + wmBase + mi * 16 + quad * 4;
            if (QKV) {
                int p = colb >> 10;          // 0=q 1=k 2=v
                int h = (colb & 1023) >> 6;
                int d = colb & 63;
                int b = rowb >> 11;
                int t = rowb & 2047;
                if (p == 2) {
                    // V transposed [bh][d][T]: r-values are t-consecutive -> ushort4
                    ushort4 pk;
                    pk.x = f2b(acc[mi][nj][0] + bias[colb]);
                    pk.y = f2b(acc[mi][nj][1] + bias[colb]);
                    pk.z = f2b(acc[mi][nj][2] + bias[colb]);
                    pk.w = f2b(acc[mi][nj][3] + bias[colb]);
                    *(ushort4*)&vb[((size_t)(b * NH + h) * HD + d) * Tseq + t] = pk;
                } else {
                    unsigned short* dst = (p == 0) ? qb : kb;
                    #pragma unroll
                    for (int r = 0; r < 4; r++)
                        dst[((size_t)(b * NH + h) * Tseq + (t + r)) * HD + d] =
                            f2b(acc[mi][nj][r] + bias[colb]);
                }
            } else {
                #pragma unroll
                for (int r = 0; r < 4; r++)
                    out[(size_t)(rowb + r) * Cdim + colb] = acc[mi][nj][r] + bias[colb];
            }
        }
    }
}

// ---------------- flash attention (causal), bf16 MFMA ----------------
// 4-wave blocks (256 thr), q-tile = 128 rows (32/wave), 64-key windows,
// double-buffered K/V LDS with 2-phase pipeline; XOR-swizzled staging;
// S^T register trick; defer-rescale.

__global__ __launch_bounds__(256, 4) void attn_kernel(const unsigned short* __restrict__ qb,
                                                      const unsigned short* __restrict__ kb,
                                                      const unsigned short* __restrict__ vt,
                                                      unsigned short* __restrict__ yb) {
    __shared__ unsigned short Ks[2][64 * 64];   // [buf][key][64d], swizzled
    __shared__ unsigned short Vs[2][64 * 64];   // [buf][d][64key], swizzled

    int tid = threadIdx.x;
    int lane = tid & 63, wave = tid >> 6;      // 4 waves
    int l15 = lane & 15, quad = lane >> 4;
    int bh = blockIdx.x;
    int qt = 15 - blockIdx.y;

    const unsigned short* Qh = qb + (size_t)bh * Tseq * HD;
    const unsigned short* Kh = kb + (size_t)bh * Tseq * HD;
    const unsigned short* Vh = vt + (size_t)bh * HD * Tseq;
    int b = bh >> 4, h = bh & 15;
    const float cexp = 0.18033688011112042f;   // 0.125 * log2(e)

    int q0 = qt * 128;
    int rb0 = q0 + wave * 32;

    short8 qf[2][2];
    #pragma unroll
    for (int mi = 0; mi < 2; mi++)
        #pragma unroll
        for (int g = 0; g < 2; g++)
            qf[mi][g] = *(const short8*)(Qh + (size_t)(rb0 + mi * 16 + l15) * HD + g * 32 + quad * 8);

    int srow = lane >> 3;
    int scol = ((lane & 7) ^ srow) * 8;
    const unsigned short* Kg0 = Kh + (size_t)(wave * 16 + srow) * HD + scol;
    const unsigned short* Vg0 = Vh + (size_t)(wave * 16 + srow) * Tseq + scol;
    unsigned short* Kl0 = &Ks[0][wave * 1024];
    unsigned short* Vl0 = &Vs[0][wave * 1024];
    unsigned short* Kl1 = &Ks[1][wave * 1024];
    unsigned short* Vl1 = &Vs[1][wave * 1024];

    int sx = l15 & 7;
    int kx0 = (quad ^ sx) * 8;
    int kx1 = ((4 + quad) ^ sx) * 8;
    int qh_ = quad >> 1, ql_ = quad & 1;

    float4v ov[2][4] = {};
    float m[2]  = {-1e30f, -1e30f};
    float lp[2] = {0.f, 0.f};

    int nw = (q0 >> 6) + 2;

    GLDS(Kg0, Kl0);                GLDS(Kg0 + 8 * HD, Kl0 + 512);
    GLDS(Vg0, Vl0);                GLDS(Vg0 + 8 * Tseq, Vl0 + 512);
    __syncthreads();

    #pragma unroll 1
    for (int it = 0; it < nw; ++it) {
        int j0 = it << 6;

        if (it + 1 < nw) {
            int jn = j0 + 64;
            unsigned short* Kl = (it & 1) ? Kl0 : Kl1;
            unsigned short* Vl = (it & 1) ? Vl0 : Vl1;
            GLDS(Kg0 + (size_t)jn * HD, Kl);
            GLDS(Kg0 + (size_t)(jn + 8) * HD, Kl + 512);
            GLDS(Vg0 + jn, Vl);
            GLDS(Vg0 + 8 * Tseq + jn, Vl + 512);
        }

        if (j0 <= rb0 + 31) {
            const unsigned short* Kl = &Ks[it & 1][0];
            const unsigned short* Vl = &Vs[it & 1][0];

            float4v st[2][4];
            #pragma unroll
            for (int mi = 0; mi < 2; mi++)
                #pragma unroll
                for (int kg = 0; kg < 4; kg++)
                    st[mi][kg] = (float4v){0.f, 0.f, 0.f, 0.f};
            #pragma unroll
            for (int kg = 0; kg < 4; kg++) {
                int krow = kg * 1024 + l15 * 64;
                short8 kf0 = *(const short8*)&Kl[krow + kx0];
                short8 kf1 = *(const short8*)&Kl[krow + kx1];
                st[0][kg] = __builtin_amdgcn_mfma_f32_16x16x32_bf16(kf0, qf[0][0], st[0][kg], 0, 0, 0);
                st[0][kg] = __builtin_amdgcn_mfma_f32_16x16x32_bf16(kf1, qf[0][1], st[0][kg], 0, 0, 0);
                st[1][kg] = __builtin_amdgcn_mfma_f32_16x16x32_bf16(kf0, qf[1][0], st[1][kg], 0, 0, 0);
                st[1][kg] = __builtin_amdgcn_mfma_f32_16x16x32_bf16(kf1, qf[1][1], st[1][kg], 0, 0, 0);
            }

            if (j0 + 63 > rb0) {
                #pragma unroll
                for (int mi = 0; mi < 2; mi++) {
                    int qrow = rb0 + mi * 16 + l15;
                    #pragma unroll
                    for (int kg = 0; kg < 4; kg++) {
                        int keyb = j0 + kg * 16 + quad * 4;
                        #pragma unroll
                        for (int r = 0; r < 4; r++)
                            if (keyb + r > qrow) st[mi][kg][r] = -1e30f;
                    }
                }
            }

            short4v pf[2][4];
            #pragma unroll
            for (int mi = 0; mi < 2; mi++) {
                float mx = st[mi][0][0];
                #pragma unroll
                for (int kg = 0; kg < 4; kg++)
                    #pragma unroll
                    for (int r = 0; r < 4; r++)
                        mx = fmaxf(mx, st[mi][kg][r]);
                mx = fmaxf(mx, __shfl_xor(mx, 16));
                mx = fmaxf(mx, __shfl_xor(mx, 32));
                if (__any(mx > m[mi] + 16.0f)) {
                    float mn = fmaxf(m[mi], mx);
                    float alv = __builtin_amdgcn_exp2f((m[mi] - mn) * cexp);
                    m[mi] = mn;
                    lp[mi] *= alv;
                    float ar_[4];
                    #pragma unroll
                    for (int r = 0; r < 4; r++)
                        ar_[r] = __shfl(alv, quad * 4 + r);
                    #pragma unroll
                    for (int dg = 0; dg < 4; dg++)
                        #pragma unroll
                        for (int r = 0; r < 4; r++)
                            ov[mi][dg][r] *= ar_[r];
                }
                float mc = -m[mi] * cexp;
                float sum = 0.f;
                #pragma unroll
                for (int kg = 0; kg < 4; kg++) {
                    float p0 = __builtin_amdgcn_exp2f(__builtin_fmaf(st[mi][kg][0], cexp, mc));
                    float p1 = __builtin_amdgcn_exp2f(__builtin_fmaf(st[mi][kg][1], cexp, mc));
                    float p2 = __builtin_amdgcn_exp2f(__builtin_fmaf(st[mi][kg][2], cexp, mc));
                    float p3 = __builtin_amdgcn_exp2f(__builtin_fmaf(st[mi][kg][3], cexp, mc));
                    sum += (p0 + p1) + (p2 + p3);
                    union { unsigned u[2]; short4v s; } pk_;
                    pk_.u[0] = pk2bf(p0, p1);
                    pk_.u[1] = pk2bf(p2, p3);
                    pf[mi][kg] = pk_.s;
                }
                lp[mi] += sum;
            }

            #pragma unroll
            for (int kg = 0; kg < 4; kg++) {
                int vx = (((kg * 2 + qh_) ^ sx) << 3) + ql_ * 4;
                #pragma unroll
                for (int dg = 0; dg < 4; dg++) {
                    short4v vf = *(const short4v*)&Vl[dg * 1024 + l15 * 64 + vx];
                    ov[0][dg] = __builtin_amdgcn_mfma_f32_16x16x16bf16_1k(pf[0][kg], vf, ov[0][dg], 0, 0, 0);
                    ov[1][dg] = __builtin_amdgcn_mfma_f32_16x16x16bf16_1k(pf[1][kg], vf, ov[1][dg], 0, 0, 0);
                }
            }
        }

        __syncthreads();
    }

    #pragma unroll
    for (int mi = 0; mi < 2; mi++) {
        float lf = lp[mi];
        lf += __shfl_xor(lf, 16);
        lf += __shfl_xor(lf, 32);
        float rinv[4];
        #pragma unroll
        for (int r = 0; r < 4; r++)
            rinv[r] = 1.0f / __shfl(lf, quad * 4 + r);
        #pragma unroll
        for (int dg = 0; dg < 4; dg++)
            #pragma unroll
            for (int r = 0; r < 4; r++) {
                int t = rb0 + mi * 16 + quad * 4 + r;
                yb[((size_t)b * Tseq + t) * Cdim + h * HD + dg * 16 + l15] =
                    f2b(ov[mi][dg][r] * rinv[r]);
            }
    }
}

extern "C" void kernel_launch(void* const* d_in, const int* in_sizes, int n_in,
                              void* d_out, int out_size, void* d_ws, size_t ws_size,
                              hipStream_t stream) {
    const float* x  = (const float*)d_in[0];
    const float* Wa = (const float*)d_in[1];
    const float* ba = (const float*)d_in[2];
    const float* Wp = (const float*)d_in[3];
    const float* bp = (const float*)d_in[4];
    float* out = (float*)d_out;

    unsigned short* ws = (unsigned short*)d_ws;
    unsigned short* xb  = ws;                          // 8192*1024
    unsigned short* Wat = xb  + (size_t)Mrows * Cdim;  // 3072*1024
    unsigned short* Wpt = Wat + (size_t)N3C * Cdim;    // 1024*1024
    unsigned short* qb  = Wpt + (size_t)Cdim * Cdim;   // [bh][T][HD]
    unsigned short* kb  = qb  + (size_t)Bsz * NH * Tseq * HD;   // [bh][T][HD]
    unsigned short* vb  = kb  + (size_t)Bsz * NH * Tseq * HD;   // [bh][HD][T]  (transposed)
    unsigned short* yb  = vb  + (size_t)Bsz * NH * Tseq * HD;

    int nx = Mrows * Cdim;
    cast_kernel<<<nx / 4 / 256, 256, 0, stream>>>(x, xb, nx);
    transpose_cast<<<dim3(N3C / 32, Cdim / 32), 256, 0, stream>>>(Wa, Wat, Cdim, N3C);
    transpose_cast<<<dim3(Cdim / 32, Cdim / 32), 256, 0, stream>>>(Wp, Wpt, Cdim, Cdim);

    // QKV: 256x256 tiles -> 32 rowblks x 12 colblks = 384 blocks
    gemm2p<8, 256, true><<<384, 512, 0, stream>>>(xb, Wat, ba, qb, kb, vb, nullptr);

    attn_kernel<<<dim3(Bsz * NH, 16), 256, 0, stream>>>(qb, kb, vb, yb);

    // proj: 256x128 tiles -> 32 rowblks x 8 colblks = 256 blocks (1 exact round)
    gemm2p<4, 128, false><<<256, 512, 0, stream>>>(yb, Wpt, bp, nullptr, nullptr, nullptr, out);
}

// Round 8
// 242.605 us; speedup vs baseline: 1.0800x; 1.0466x over previous
//
#include <hip/hip_runtime.h>
#include <hip/hip_bf16.h>

// Problem constants
#define Bsz 4
#define Tseq 2048
#define Cdim 1024
#define NH 16
#define HD 64
#define Mrows (Bsz*Tseq)      // 8192
#define N3C (3*Cdim)          // 3072

typedef __attribute__((ext_vector_type(8))) short short8;
typedef __attribute__((ext_vector_type(4))) short short4v;
typedef __attribute__((ext_vector_type(4))) float float4v;

__device__ __forceinline__ unsigned short f2b(float f) {
    union { float f; unsigned u; } x; x.f = f;
    unsigned u = x.u;
    u += 0x7fff + ((u >> 16) & 1);   // true RNE to bf16
    return (unsigned short)(u >> 16);
}

// pack 2 floats -> bf16x2 dword (RNE)
__device__ __forceinline__ unsigned pk2bf(float a, float b) {
#if __has_builtin(__builtin_amdgcn_cvt_pk_bf16_f32)
    auto w = __builtin_amdgcn_cvt_pk_bf16_f32(a, b);
    unsigned u; __builtin_memcpy(&u, &w, 4);
    return u;
#else
    return (unsigned)f2b(a) | ((unsigned)f2b(b) << 16);
#endif
}

// async global->LDS, 16B per lane; lds dst must be wave-uniform (HW adds lane*16)
#define GLDS(gp, lp) __builtin_amdgcn_global_load_lds(                         \
    (const __attribute__((address_space(1))) unsigned*)(gp),                   \
    (__attribute__((address_space(3))) unsigned*)(lp), 16, 0, 0)

// ---------------- cast x: f32 -> bf16 ----------------
__global__ __launch_bounds__(256) void cast_kernel(const float* __restrict__ in,
                                                   unsigned short* __restrict__ out, int n) {
    int i = (blockIdx.x * 256 + threadIdx.x) * 4;
    if (i < n) {
        float4 v = *reinterpret_cast<const float4*>(in + i);
        ushort4 o;
        o.x = f2b(v.x); o.y = f2b(v.y); o.z = f2b(v.z); o.w = f2b(v.w);
        *reinterpret_cast<ushort4*>(out + i) = o;
    }
}

// ---------------- transpose + cast: W[K][N] f32 -> Wt[N][K] bf16 ----------------
__global__ __launch_bounds__(256) void transpose_cast(const float* __restrict__ in,
                                                      unsigned short* __restrict__ out,
                                                      int K, int N) {
    __shared__ float tile[32][33];
    int n0 = blockIdx.x * 32, k0 = blockIdx.y * 32;
    int tx = threadIdx.x & 31, ty = threadIdx.x >> 5;   // 8 rows per pass
    #pragma unroll
    for (int i = 0; i < 32; i += 8)
        tile[ty + i][tx] = in[(k0 + ty + i) * N + n0 + tx];
    __syncthreads();
    #pragma unroll
    for (int i = 0; i < 32; i += 8)
        out[(size_t)(n0 + ty + i) * K + k0 + tx] = f2b(tile[tx][ty + i]);
}

// ====== bf16 MFMA GEMM, 3-slot K-slice rotation, unpinned schedule ======
// BM=256, BN=128, BK=64 as two 32-wide K-slices; 512 thr (8 waves, 4M x 2N,
// wave tile 64x64, acc[4][4]).  LDS = 3 slots x (A 256x32 + B 128x32) = 72 KiB
// -> TWO blocks/CU (4 waves/SIMD) for cross-block phase-offset overlap.
// Phase p (one per slice, 32 total): read slot p%3 (8 ds_read_b128),
// stage slice p+2 -> slot (p+2)%3 (3 GLDS), 16 MFMA (setprio-wrapped),
// vmcnt(3) [drains slice p+1; slice p+2 stays in flight], ONE s_barrier.
// One-barrier safety: the slot overwritten by phase p's stage was read in
// phase p-1, whose end barrier already guaranteed those reads completed.
// NO lgkmcnt(0)/sched_barrier pinning: ds_reads are plain C++ loads, the
// compiler inserts fine-grained lgkmcnt between reads and dependent MFMAs
// (full-drain pinning was the m141-style regression common to r3/r4/r6).
// Tail exact: phases 30/31 skip staging; vmcnt(0) at phase 30. No wrap DMAs.
// Both-sides 16B-granule swizzle (granule ^ ((row>>1)&3)), proven in r6/r7.

template<bool QKV>
__global__ __launch_bounds__(512, 4) void gemm3s(const unsigned short* __restrict__ A,
                                                 const unsigned short* __restrict__ Bt,
                                                 const float* __restrict__ bias,
                                                 unsigned short* __restrict__ qb,
                                                 unsigned short* __restrict__ kb,
                                                 unsigned short* __restrict__ vb,
                                                 float* __restrict__ out) {
    __shared__ unsigned short As[3][256 * 32];   // 48 KiB
    __shared__ unsigned short Bs[3][128 * 32];   // 24 KiB

    int tid = threadIdx.x;
    int lane = tid & 63, wave = tid >> 6;        // 8 waves
    int wm = wave >> 1, wn = wave & 1;           // 4M x 2N
    int l15 = lane & 15, quad = lane >> 4;

    // XCD-panel swizzle: 32 row-blocks, 4 per XCD (grid % 8 == 0)
    int f = blockIdx.x;
    int xcd = f & 7, slot = f >> 3;
    int rowblk = xcd * 4 + (slot & 3);           // 0..31
    int colblk = slot >> 2;
    int row0 = rowblk * 256;
    int col0 = colblk * 128;

    // staging: lane -> row +(lane>>2) in 16-row group, granule lane&3;
    // source granule pre-swizzled: (lane&3) ^ ((lane>>3)&3)
    int srow4 = lane >> 2;
    int gsrc = ((lane & 3) ^ ((lane >> 3) & 3)) * 8;
    const unsigned short* Ag = A + (size_t)(row0 + srow4) * Cdim + gsrc;
    const unsigned short* Bg = Bt + (size_t)(col0 + srow4) * Cdim + gsrc;

    // stage one K-slice (k-offset kk_ in shorts) into slot sl_: 3 GLDS/thread
    #define STG3(kk_, sl_) do {                                                \
        GLDS(Ag + (size_t)(wave * 16) * Cdim + (kk_),                          \
             &As[sl_][(wave * 16) * 32]);                                      \
        GLDS(Ag + (size_t)(128 + wave * 16) * Cdim + (kk_),                    \
             &As[sl_][(128 + wave * 16) * 32]);                                \
        GLDS(Bg + (size_t)(wave * 16) * Cdim + (kk_),                          \
             &Bs[sl_][(wave * 16) * 32]);                                      \
    } while (0)

    float4v acc[4][4] = {};

    // prologue: slice 0 -> slot 0, slice 1 -> slot 1; drain slice 0
    STG3(0, 0);
    STG3(32, 1);
    asm volatile("s_waitcnt vmcnt(3)" ::: "memory");
    __builtin_amdgcn_s_barrier();

    // frag-read swizzle: granule = quad ^ ((row>>1)&3) = quad ^ ((l15>>1)&3)
    int gq0 = (quad ^ ((l15 >> 1) & 3)) * 8;
    int afb = (wm * 64 + l15) * 32 + gq0;        // + mi*512
    int bfb = (wn * 64 + l15) * 32 + gq0;        // + nj*512

    int sl = 0, sp = 2;                          // read slot, stage slot
    #pragma unroll 1
    for (int p = 0; p < 30; ++p) {
        const unsigned short* Asl = &As[sl][0];
        const unsigned short* Bsl = &Bs[sl][0];
        short8 af[4], bf[4];
        #pragma unroll
        for (int mi = 0; mi < 4; mi++)
            af[mi] = *(const short8*)&Asl[afb + mi * 512];
        #pragma unroll
        for (int nj = 0; nj < 4; nj++)
            bf[nj] = *(const short8*)&Bsl[bfb + nj * 512];

        STG3((p + 2) * 32, sp);                  // slice p+2 -> slot (p+2)%3

        __builtin_amdgcn_s_setprio(1);
        #pragma unroll
        for (int mi = 0; mi < 4; mi++)
            #pragma unroll
            for (int nj = 0; nj < 4; nj++)
                acc[mi][nj] = __builtin_amdgcn_mfma_f32_16x16x32_bf16(af[mi], bf[nj], acc[mi][nj], 0, 0, 0);
        __builtin_amdgcn_s_setprio(0);

        // drain slice p+1 (next phase's data); slice p+2 stays in flight
        asm volatile("s_waitcnt vmcnt(3)" ::: "memory");
        __builtin_amdgcn_s_barrier();
        sl = (sl == 2) ? 0 : sl + 1;
        sp = (sp == 2) ? 0 : sp + 1;
    }
    // phase 30: no stage; drain slice 31 fully
    {
        const unsigned short* Asl = &As[sl][0];
        const unsigned short* Bsl = &Bs[sl][0];
        short8 af[4], bf[4];
        #pragma unroll
        for (int mi = 0; mi < 4; mi++)
            af[mi] = *(const short8*)&Asl[afb + mi * 512];
        #pragma unroll
        for (int nj = 0; nj < 4; nj++)
            bf[nj] = *(const short8*)&Bsl[bfb + nj * 512];
        __builtin_amdgcn_s_setprio(1);
        #pragma unroll
        for (int mi = 0; mi < 4; mi++)
            #pragma unroll
            for (int nj = 0; nj < 4; nj++)
                acc[mi][nj] = __builtin_amdgcn_mfma_f32_16x16x32_bf16(af[mi], bf[nj], acc[mi][nj], 0, 0, 0);
        __builtin_amdgcn_s_setprio(0);
        asm volatile("s_waitcnt vmcnt(0)" ::: "memory");
        __builtin_amdgcn_s_barrier();
        sl = (sl == 2) ? 0 : sl + 1;
    }
    // phase 31: last slice; no stage, no wait
    {
        const unsigned short* Asl = &As[sl][0];
        const unsigned short* Bsl = &Bs[sl][0];
        short8 af[4], bf[4];
        #pragma unroll
        for (int mi = 0; mi < 4; mi++)
            af[mi] = *(const short8*)&Asl[afb + mi * 512];
        #pragma unroll
        for (int nj = 0; nj < 4; nj++)
            bf[nj] = *(const short8*)&Bsl[bfb + nj * 512];
        #pragma unroll
        for (int mi = 0; mi < 4; mi++)
            #pragma unroll
            for (int nj = 0; nj < 4; nj++)
                acc[mi][nj] = __builtin_amdgcn_mfma_f32_16x16x32_bf16(af[mi], bf[nj], acc[mi][nj], 0, 0, 0);
    }
    #undef STG3

    // epilogue: wave tile 64x64 at (wm*64, wn*64)
    #pragma unroll
    for (int mi = 0; mi < 4; mi++) {
        #pragma unroll
        for (int nj = 0; nj < 4; nj++) {
            int colb = col0 + wn * 64 + nj * 16 + l15;
            int rowb = row0 + wm * 64 + mi * 16 + quad * 4;
            if (QKV) {
                int p = colb >> 10;          // 0=q 1=k 2=v
                int h = (colb & 1023) >> 6;
                int d = colb & 63;
                int b = rowb >> 11;
                int t = rowb & 2047;
                if (p == 2) {
                    // V transposed [bh][d][T]: r-values are t-consecutive -> ushort4
                    ushort4 pk;
                    pk.x = f2b(acc[mi][nj][0] + bias[colb]);
                    pk.y = f2b(acc[mi][nj][1] + bias[colb]);
                    pk.z = f2b(acc[mi][nj][2] + bias[colb]);
                    pk.w = f2b(acc[mi][nj][3] + bias[colb]);
                    *(ushort4*)&vb[((size_t)(b * NH + h) * HD + d) * Tseq + t] = pk;
                } else {
                    unsigned short* dst = (p == 0) ? qb : kb;
                    #pragma unroll
                    for (int r = 0; r < 4; r++)
                        dst[((size_t)(b * NH + h) * Tseq + (t + r)) * HD + d] =
                            f2b(acc[mi][nj][r] + bias[colb]);
                }
            } else {
                #pragma unroll
                for (int r = 0; r < 4; r++)
                    out[(size_t)(rowb + r) * Cdim + colb] = acc[mi][nj][r] + bias[colb];
            }
        }
    }
}

// ---------------- flash attention (causal), bf16 MFMA ----------------
// 4-wave blocks (256 thr), q-tile = 128 rows (32/wave), 64-key windows,
// double-buffered K/V LDS with 2-phase pipeline; XOR-swizzled staging;
// S^T register trick; defer-rescale.

__global__ __launch_bounds__(256, 4) void attn_kernel(const unsigned short* __restrict__ qb,
                                                      const unsigned short* __restrict__ kb,
                                                      const unsigned short* __restrict__ vt,
                                                      unsigned short* __restrict__ yb) {
    __shared__ unsigned short Ks[2][64 * 64];   // [buf][key][64d], swizzled
    __shared__ unsigned short Vs[2][64 * 64];   // [buf][d][64key], swizzled

    int tid = threadIdx.x;
    int lane = tid & 63, wave = tid >> 6;      // 4 waves
    int l15 = lane & 15, quad = lane >> 4;
    int bh = blockIdx.x;
    int qt = 15 - blockIdx.y;

    const unsigned short* Qh = qb + (size_t)bh * Tseq * HD;
    const unsigned short* Kh = kb + (size_t)bh * Tseq * HD;
    const unsigned short* Vh = vt + (size_t)bh * HD * Tseq;
    int b = bh >> 4, h = bh & 15;
    const float cexp = 0.18033688011112042f;   // 0.125 * log2(e)

    int q0 = qt * 128;
    int rb0 = q0 + wave * 32;

    short8 qf[2][2];
    #pragma unroll
    for (int mi = 0; mi < 2; mi++)
        #pragma unroll
        for (int g = 0; g < 2; g++)
            qf[mi][g] = *(const short8*)(Qh + (size_t)(rb0 + mi * 16 + l15) * HD + g * 32 + quad * 8);

    int srow = lane >> 3;
    int scol = ((lane & 7) ^ srow) * 8;
    const unsigned short* Kg0 = Kh + (size_t)(wave * 16 + srow) * HD + scol;
    const unsigned short* Vg0 = Vh + (size_t)(wave * 16 + srow) * Tseq + scol;
    unsigned short* Kl0 = &Ks[0][wave * 1024];
    unsigned short* Vl0 = &Vs[0][wave * 1024];
    unsigned short* Kl1 = &Ks[1][wave * 1024];
    unsigned short* Vl1 = &Vs[1][wave * 1024];

    int sx = l15 & 7;
    int kx0 = (quad ^ sx) * 8;
    int kx1 = ((4 + quad) ^ sx) * 8;
    int qh_ = quad >> 1, ql_ = quad & 1;

    float4v ov[2][4] = {};
    float m[2]  = {-1e30f, -1e30f};
    float lp[2] = {0.f, 0.f};

    int nw = (q0 >> 6) + 2;

    GLDS(Kg0, Kl0);                GLDS(Kg0 + 8 * HD, Kl0 + 512);
    GLDS(Vg0, Vl0);                GLDS(Vg0 + 8 * Tseq, Vl0 + 512);
    __syncthreads();

    #pragma unroll 1
    for (int it = 0; it < nw; ++it) {
        int j0 = it << 6;

        if (it + 1 < nw) {
            int jn = j0 + 64;
            unsigned short* Kl = (it & 1) ? Kl0 : Kl1;
            unsigned short* Vl = (it & 1) ? Vl0 : Vl1;
            GLDS(Kg0 + (size_t)jn * HD, Kl);
            GLDS(Kg0 + (size_t)(jn + 8) * HD, Kl + 512);
            GLDS(Vg0 + jn, Vl);
            GLDS(Vg0 + 8 * Tseq + jn, Vl + 512);
        }

        if (j0 <= rb0 + 31) {
            const unsigned short* Kl = &Ks[it & 1][0];
            const unsigned short* Vl = &Vs[it & 1][0];

            float4v st[2][4];
            #pragma unroll
            for (int mi = 0; mi < 2; mi++)
                #pragma unroll
                for (int kg = 0; kg < 4; kg++)
                    st[mi][kg] = (float4v){0.f, 0.f, 0.f, 0.f};
            #pragma unroll
            for (int kg = 0; kg < 4; kg++) {
                int krow = kg * 1024 + l15 * 64;
                short8 kf0 = *(const short8*)&Kl[krow + kx0];
                short8 kf1 = *(const short8*)&Kl[krow + kx1];
                st[0][kg] = __builtin_amdgcn_mfma_f32_16x16x32_bf16(kf0, qf[0][0], st[0][kg], 0, 0, 0);
                st[0][kg] = __builtin_amdgcn_mfma_f32_16x16x32_bf16(kf1, qf[0][1], st[0][kg], 0, 0, 0);
                st[1][kg] = __builtin_amdgcn_mfma_f32_16x16x32_bf16(kf0, qf[1][0], st[1][kg], 0, 0, 0);
                st[1][kg] = __builtin_amdgcn_mfma_f32_16x16x32_bf16(kf1, qf[1][1], st[1][kg], 0, 0, 0);
            }

            if (j0 + 63 > rb0) {
                #pragma unroll
                for (int mi = 0; mi < 2; mi++) {
                    int qrow = rb0 + mi * 16 + l15;
                    #pragma unroll
                    for (int kg = 0; kg < 4; kg++) {
                        int keyb = j0 + kg * 16 + quad * 4;
                        #pragma unroll
                        for (int r = 0; r < 4; r++)
                            if (keyb + r > qrow) st[mi][kg][r] = -1e30f;
                    }
                }
            }

            short4v pf[2][4];
            #pragma unroll
            for (int mi = 0; mi < 2; mi++) {
                float mx = st[mi][0][0];
                #pragma unroll
                for (int kg = 0; kg < 4; kg++)
                    #pragma unroll
                    for (int r = 0; r < 4; r++)
                        mx = fmaxf(mx, st[mi][kg][r]);
                mx = fmaxf(mx, __shfl_xor(mx, 16));
                mx = fmaxf(mx, __shfl_xor(mx, 32));
                if (__any(mx > m[mi] + 16.0f)) {
                    float mn = fmaxf(m[mi], mx);
                    float alv = __builtin_amdgcn_exp2f((m[mi] - mn) * cexp);
                    m[mi] = mn;
                    lp[mi] *= alv;
                    float ar_[4];
                    #pragma unroll
                    for (int r = 0; r < 4; r++)
                        ar_[r] = __shfl(alv, quad * 4 + r);
                    #pragma unroll
                    for (int dg = 0; dg < 4; dg++)
                        #pragma unroll
                        for (int r = 0; r < 4; r++)
                            ov[mi][dg][r] *= ar_[r];
                }
                float mc = -m[mi] * cexp;
                float sum = 0.f;
                #pragma unroll
                for (int kg = 0; kg < 4; kg++) {
                    float p0 = __builtin_amdgcn_exp2f(__builtin_fmaf(st[mi][kg][0], cexp, mc));
                    float p1 = __builtin_amdgcn_exp2f(__builtin_fmaf(st[mi][kg][1], cexp, mc));
                    float p2 = __builtin_amdgcn_exp2f(__builtin_fmaf(st[mi][kg][2], cexp, mc));
                    float p3 = __builtin_amdgcn_exp2f(__builtin_fmaf(st[mi][kg][3], cexp, mc));
                    sum += (p0 + p1) + (p2 + p3);
                    union { unsigned u[2]; short4v s; } pk_;
                    pk_.u[0] = pk2bf(p0, p1);
                    pk_.u[1] = pk2bf(p2, p3);
                    pf[mi][kg] = pk_.s;
                }
                lp[mi] += sum;
            }

            #pragma unroll
            for (int kg = 0; kg < 4; kg++) {
                int vx = (((kg * 2 + qh_) ^ sx) << 3) + ql_ * 4;
                #pragma unroll
                for (int dg = 0; dg < 4; dg++) {
                    short4v vf = *(const short4v*)&Vl[dg * 1024 + l15 * 64 + vx];
                    ov[0][dg] = __builtin_amdgcn_mfma_f32_16x16x16bf16_1k(pf[0][kg], vf, ov[0][dg], 0, 0, 0);
                    ov[1][dg] = __builtin_amdgcn_mfma_f32_16x16x16bf16_1k(pf[1][kg], vf, ov[1][dg], 0, 0, 0);
                }
            }
        }

        __syncthreads();
    }

    #pragma unroll
    for (int mi = 0; mi < 2; mi++) {
        float lf = lp[mi];
        lf += __shfl_xor(lf, 16);
        lf += __shfl_xor(lf, 32);
        float rinv[4];
        #pragma unroll
        for (int r = 0; r < 4; r++)
            rinv[r] = 1.0f / __shfl(lf, quad * 4 + r);
        #pragma unroll
        for (int dg = 0; dg < 4; dg++)
            #pragma unroll
            for (int r = 0; r < 4; r++) {
                int t = rb0 + mi * 16 + quad * 4 + r;
                yb[((size_t)b * Tseq + t) * Cdim + h * HD + dg * 16 + l15] =
                    f2b(ov[mi][dg][r] * rinv[r]);
            }
    }
}

extern "C" void kernel_launch(void* const* d_in, const int* in_sizes, int n_in,
                              void* d_out, int out_size, void* d_ws, size_t ws_size,
                              hipStream_t stream) {
    const float* x  = (const float*)d_in[0];
    const float* Wa = (const float*)d_in[1];
    const float* ba = (const float*)d_in[2];
    const float* Wp = (const float*)d_in[3];
    const float* bp = (const float*)d_in[4];
    float* out = (float*)d_out;

    unsigned short* ws = (unsigned short*)d_ws;
    unsigned short* xb  = ws;                          // 8192*1024
    unsigned short* Wat = xb  + (size_t)Mrows * Cdim;  // 3072*1024
    unsigned short* Wpt = Wat + (size_t)N3C * Cdim;    // 1024*1024
    unsigned short* qb  = Wpt + (size_t)Cdim * Cdim;   // [bh][T][HD]
    unsigned short* kb  = qb  + (size_t)Bsz * NH * Tseq * HD;   // [bh][T][HD]
    unsigned short* vb  = kb  + (size_t)Bsz * NH * Tseq * HD;   // [bh][HD][T]  (transposed)
    unsigned short* yb  = vb  + (size_t)Bsz * NH * Tseq * HD;

    int nx = Mrows * Cdim;
    cast_kernel<<<nx / 4 / 256, 256, 0, stream>>>(x, xb, nx);
    transpose_cast<<<dim3(N3C / 32, Cdim / 32), 256, 0, stream>>>(Wa, Wat, Cdim, N3C);
    transpose_cast<<<dim3(Cdim / 32, Cdim / 32), 256, 0, stream>>>(Wp, Wpt, Cdim, Cdim);

    // QKV: 256x128 tiles -> 32 rowblks x 24 colblks = 768 blocks (2 blocks/CU)
    gemm3s<true><<<768, 512, 0, stream>>>(xb, Wat, ba, qb, kb, vb, nullptr);

    attn_kernel<<<dim3(Bsz * NH, 16), 256, 0, stream>>>(qb, kb, vb, yb);

    // proj: 256x128 tiles -> 32 rowblks x 8 colblks = 256 blocks
    gemm3s<false><<<256, 512, 0, stream>>>(yb, Wpt, bp, nullptr, nullptr, nullptr, out);
}